// Round 15
// baseline (121.302 us; speedup 1.0000x reference)
//
#include <hip/hip_runtime.h>
#include <hip/hip_bf16.h>
#include <cstdint>

typedef __bf16 bf16_t;
typedef __bf16 bf16x8 __attribute__((ext_vector_type(8)));
typedef __bf16 bf16x4 __attribute__((ext_vector_type(4)));
typedef __bf16 bf16x2 __attribute__((ext_vector_type(2)));
typedef float  f32x4  __attribute__((ext_vector_type(4)));
typedef float  f32x16 __attribute__((ext_vector_type(16)));
typedef unsigned uint4v __attribute__((ext_vector_type(4)));

#define AS1 __attribute__((address_space(1)))
#define AS3 __attribute__((address_space(3)))

static __device__ __forceinline__ void gld_lds16(const void* g, void* l) {
  __builtin_amdgcn_global_load_lds((AS1 void*)g, (AS3 void*)l, 16, 0, 0);
}

// truncation-pack two f32 -> bf16x2 word via one v_perm_b32 (lo=a, hi=b).
static __device__ __forceinline__ unsigned pk2t(float a, float b) {
  return __builtin_amdgcn_perm(__builtin_bit_cast(unsigned, a),
                               __builtin_bit_cast(unsigned, b), 0x03020706u);
}

// ---------------- fused prep: convert x (16B stores) + transpose weights -----
// blocks [0,2048): convert x f32->bf16, 8 elems/lane
// blocks [2048,5120): transpose wqkv ; [5120,6144): transpose wo
__global__ __launch_bounds__(256) void prep_k(const float* __restrict__ x,
                                              bf16_t* __restrict__ xb,
                                              const float* __restrict__ wqkv,
                                              bf16_t* __restrict__ wqkvT,
                                              const float* __restrict__ wo,
                                              bf16_t* __restrict__ woT) {
  int bid = blockIdx.x;
  if (bid < 2048) {
    const int i = bid * 256 + threadIdx.x;
    float4 v0 = ((const float4*)x)[(size_t)i * 2];
    float4 v1 = ((const float4*)x)[(size_t)i * 2 + 1];
    bf16x8 o;
    o[0] = (bf16_t)v0.x; o[1] = (bf16_t)v0.y; o[2] = (bf16_t)v0.z; o[3] = (bf16_t)v0.w;
    o[4] = (bf16_t)v1.x; o[5] = (bf16_t)v1.y; o[6] = (bf16_t)v1.z; o[7] = (bf16_t)v1.w;
    *(bf16x8*)(xb + (size_t)i * 8) = o;
    return;
  }
  __shared__ float tile[32][33];
  const float* in; bf16_t* out; int N, bx, by;
  if (bid < 5120) { bid -= 2048; in = wqkv; out = wqkvT; N = 3072; bx = bid % 96; by = bid / 96; }
  else            { bid -= 5120; in = wo;   out = woT;   N = 1024; bx = bid & 31; by = bid >> 5; }
  const int t = threadIdx.x, c = t & 31, r0 = t >> 5;
#pragma unroll
  for (int i = 0; i < 4; ++i) {
    int r = r0 + i * 8;
    tile[r][c] = in[(size_t)(by * 32 + r) * N + bx * 32 + c];
  }
  __syncthreads();
#pragma unroll
  for (int i = 0; i < 4; ++i) {
    int r = r0 + i * 8;
    out[(size_t)(bx * 32 + r) * 1024 + by * 32 + c] = (bf16_t)tile[c][r];
  }
}

// ---------------- 128x128 bf16 GEMM core: single-barrier 3-buf pipeline -------
// BK=32, LDS 48KB: A bufs i%3 at +0/8192/16384, B at +24576/+8192 steps.
// Iter j: vmcnt(4) [forces stage(j) done; stage(j+1) stays in flight],
// s_barrier, THEN stage(j+2) (post-barrier => WAR-safe vs iter j-1 readers),
// ds_read frags(j), 16 MFMA. ONE barrier per iter. Tail: vmcnt(0) at NK-1.
template <int KDIM>
static __device__ __forceinline__ void gemm128_pipe(const bf16_t* __restrict__ A,
                                                    const bf16_t* __restrict__ Bt,
                                                    char* lds, f32x4 acc[4][4],
                                                    int bm, int bn) {
  constexpr int NK = KDIM / 32;
  const int t = threadIdx.x;
  const int lr = t & 15, g = (t >> 4) & 3;
  const int w = t >> 6, wr = w >> 1, wc = w & 1;

  auto bufA = [&](int i) { return lds + (i % 3) * 8192; };
  auto bufB = [&](int i) { return lds + 24576 + (i % 3) * 8192; };

  auto stage = [&](int i) {
    const int kt = i * 32;
    char* la = bufA(i);
    char* lb = bufB(i);
#pragma unroll
    for (int c = 0; c < 2; ++c) {
      const int idx = c * 256 + t;
      const int row = idx >> 2, cb = idx & 3;
      const int off = ((t & 192) + c * 256) * 16;
      gld_lds16(A  + (size_t)(bm * 128 + row) * KDIM + kt + cb * 8, la + off);
      gld_lds16(Bt + (size_t)(bn * 128 + row) * KDIM + kt + cb * 8, lb + off);
    }
  };

  stage(0);
  stage(1);

  for (int j = 0; j < NK; ++j) {
    if (j < NK - 1) asm volatile("s_waitcnt vmcnt(4)" ::: "memory");
    else            asm volatile("s_waitcnt vmcnt(0)" ::: "memory");
    __builtin_amdgcn_sched_barrier(0);
    __builtin_amdgcn_s_barrier();        // tile j resident; iter j-1 reads done
    if (j + 2 < NK) stage(j + 2);        // post-barrier: WAR-safe
    const char* laR = bufA(j);
    const char* lbR = bufB(j);
    bf16x8 af[4], bv[4];
#pragma unroll
    for (int mi = 0; mi < 4; ++mi)
      af[mi] = *(const bf16x8*)(laR + (wr * 64 + mi * 16 + lr) * 64 + g * 16);
#pragma unroll
    for (int ni = 0; ni < 4; ++ni)
      bv[ni] = *(const bf16x8*)(lbR + (wc * 64 + ni * 16 + lr) * 64 + g * 16);
    __builtin_amdgcn_s_setprio(1);
#pragma unroll
    for (int mi = 0; mi < 4; ++mi)
#pragma unroll
      for (int ni = 0; ni < 4; ++ni)
        acc[mi][ni] = __builtin_amdgcn_mfma_f32_16x16x32_bf16(af[mi], bv[ni], acc[mi][ni], 0, 0, 0);
    __builtin_amdgcn_s_setprio(0);
  }
}

// GEMM1: qkv = x @ Wqkv ; Q PRE-SCALED by log2(e)/sqrt(64); V stored with
// quad-swapped kv order so attn PV A-fragments are contiguous 16B in LDS.
__global__ __launch_bounds__(256) void gemm_qkv_k(const bf16_t* __restrict__ xb,
                                                  const bf16_t* __restrict__ wt,
                                                  bf16_t* __restrict__ Qo,
                                                  bf16_t* __restrict__ Ko,
                                                  bf16_t* __restrict__ Vto) {
  __shared__ __align__(16) char lds[49152];
  const int bm = blockIdx.x, bn = blockIdx.y;
  f32x4 acc[4][4] = {};
  gemm128_pipe<1024>(xb, wt, lds, acc, bm, bn);
  const float cs = 0.18033688011112042f;
  const int t = threadIdx.x, lr = t & 15, g = (t >> 4) & 3, w = t >> 6, wr = w >> 1, wc = w & 1;
  const int row0 = bm * 128 + wr * 64, col0 = bn * 128 + wc * 64;
#pragma unroll
  for (int mi = 0; mi < 4; ++mi) {
    const int row = row0 + mi * 16 + g * 4;
    const int b = row >> 11, s = row & 2047;
#pragma unroll
    for (int ni = 0; ni < 4; ++ni) {
      const int col = col0 + ni * 16 + lr;
      const int t3 = col >> 10, rem = col & 1023, h = rem >> 6, d = rem & 63;
      const int bh = b * 16 + h;
#pragma unroll
      for (int r = 0; r < 4; ++r) {
        const float av = acc[mi][ni][r];
        if (t3 == 0)      Qo[((size_t)bh * 2048 + s + r) * 64 + d] = (bf16_t)(av * cs);
        else if (t3 == 1) Ko[((size_t)bh * 2048 + s + r) * 64 + d] = (bf16_t)av;
        else {
          const int kv = s + r;
          const int q3 = (kv >> 2) & 7;
          const int dq = (q3 & 4) | ((q3 & 1) << 1) | ((q3 >> 1) & 1);
          const int kvp = (kv & ~31) | (dq << 2) | (kv & 3);
          Vto[((size_t)bh * 64 + d) * 2048 + kvp] = (bf16_t)av;
        }
      }
    }
  }
}

__global__ __launch_bounds__(256) void gemm_o_k(const bf16_t* __restrict__ attn,
                                                const bf16_t* __restrict__ wot,
                                                float* __restrict__ out) {
  __shared__ __align__(16) char lds[49152];
  const int bm = blockIdx.x, bn = blockIdx.y;
  f32x4 acc[4][4] = {};
  gemm128_pipe<1024>(attn, wot, lds, acc, bm, bn);
  const int t = threadIdx.x, lr = t & 15, g = (t >> 4) & 3, w = t >> 6, wr = w >> 1, wc = w & 1;
  const int row0 = bm * 128 + wr * 64, col0 = bn * 128 + wc * 64;
#pragma unroll
  for (int mi = 0; mi < 4; ++mi) {
    const int row = row0 + mi * 16 + g * 4;
#pragma unroll
    for (int ni = 0; ni < 4; ++ni) {
      const int col = col0 + ni * 16 + lr;
#pragma unroll
      for (int r = 0; r < 4; ++r)
        out[(size_t)(row + r) * 1024 + col] = acc[mi][ni][r];
    }
  }
}

// ---------------- flash attention: single-barrier 3-buf pipeline --------------
// grid (16,32) XCD-swizzled. Q(pre-scaled),K: [bh][2048][64]; Vperm: [bh][64][2048']
// (kv quad-swapped); Ao: [b][s][h*64+d].
// 3 K-bufs (0-24K) + 3 V-bufs (24-48K). Iter j: vmcnt(4/2/0) [forces V(j),K(j+1)
// done; V(j+1),K(j+2) stay in flight], s_barrier, THEN stageV(j+2)/stageK(j+3)
// (post-barrier => WAR-safe: those bufs were last read at iter j-1),
// qk(j+1) [MFMA] || softmax(j)+PV(j). ONE barrier per iter.
__global__ __launch_bounds__(256, 2) void attn_k(const bf16_t* __restrict__ Q,
                                                 const bf16_t* __restrict__ K,
                                                 const bf16_t* __restrict__ Vt,
                                                 bf16_t* __restrict__ Ao) {
  __shared__ __align__(16) char smem[49152];  // kb0..2 @0/8K/16K, vb0..2 @24/32/40K
  const int t = threadIdx.x, w = t >> 6, l = t & 63;
  const int ql = l & 31, hi = l >> 5;
  const int orig = blockIdx.y * 16 + blockIdx.x;
  const int swz = (orig & 7) * 64 + (orig >> 3);
  const int qblk = swz & 15, bh = swz >> 4;
  const int b = bh >> 4, h = bh & 15;
  const bf16_t* Qb = Q  + (size_t)bh * 2048 * 64;
  const bf16_t* Kb = K  + (size_t)bh * 2048 * 64;
  const bf16_t* Vb = Vt + (size_t)bh * 64 * 2048;
  const int q0 = qblk * 128 + w * 32;

  const bf16_t* ksrc = Kb + (size_t)l * 64 + w * 8;
  const bf16_t* vsrc = Vb + (size_t)l * 2048 + w * 8;

  const bf16_t* qp = Qb + (size_t)(q0 + ql) * 64 + hi * 8;
  const bf16x8 qf0 = *(const bf16x8*)(qp);
  const bf16x8 qf1 = *(const bf16x8*)(qp + 16);
  const bf16x8 qf2 = *(const bf16x8*)(qp + 32);
  const bf16x8 qf3 = *(const bf16x8*)(qp + 48);

  bf16x8 ones;
#pragma unroll
  for (int i = 0; i < 8; ++i) ones[i] = (bf16_t)1.0f;

  f32x16 ot0 = {}, ot1 = {}, otls = {};

  auto stageK = [&](int tile, char* dst) {
    const bf16_t* ks = ksrc + (size_t)tile * 4096;
    gld_lds16(ks,      dst + w * 1024);
    gld_lds16(ks + 32, dst + (4 + w) * 1024);
  };
  auto stageV = [&](int tile, char* dst) {
    const bf16_t* vs = vsrc + (size_t)tile * 64;
    gld_lds16(vs,      dst + w * 1024);
    gld_lds16(vs + 32, dst + (4 + w) * 1024);
  };
  auto qk = [&](const char* kbuf, f32x16& sa, f32x16& sb) {
    const bf16x8 ka0 = *(const bf16x8*)(kbuf + (0 + hi) * 1024 + ql * 16);
    const bf16x8 ka1 = *(const bf16x8*)(kbuf + (2 + hi) * 1024 + ql * 16);
    const bf16x8 ka2 = *(const bf16x8*)(kbuf + (4 + hi) * 1024 + ql * 16);
    const bf16x8 ka3 = *(const bf16x8*)(kbuf + (6 + hi) * 1024 + ql * 16);
    sa = __builtin_amdgcn_mfma_f32_32x32x16_bf16(ka0, qf0, sa, 0, 0, 0);
    sa = __builtin_amdgcn_mfma_f32_32x32x16_bf16(ka1, qf1, sa, 0, 0, 0);
    sa = __builtin_amdgcn_mfma_f32_32x32x16_bf16(ka2, qf2, sa, 0, 0, 0);
    sa = __builtin_amdgcn_mfma_f32_32x32x16_bf16(ka3, qf3, sa, 0, 0, 0);
    const bf16x8 kb0f = *(const bf16x8*)(kbuf + (0 + hi) * 1024 + 512 + ql * 16);
    const bf16x8 kb1f = *(const bf16x8*)(kbuf + (2 + hi) * 1024 + 512 + ql * 16);
    const bf16x8 kb2f = *(const bf16x8*)(kbuf + (4 + hi) * 1024 + 512 + ql * 16);
    const bf16x8 kb3f = *(const bf16x8*)(kbuf + (6 + hi) * 1024 + 512 + ql * 16);
    sb = __builtin_amdgcn_mfma_f32_32x32x16_bf16(kb0f, qf0, sb, 0, 0, 0);
    sb = __builtin_amdgcn_mfma_f32_32x32x16_bf16(kb1f, qf1, sb, 0, 0, 0);
    sb = __builtin_amdgcn_mfma_f32_32x32x16_bf16(kb2f, qf2, sb, 0, 0, 0);
    sb = __builtin_amdgcn_mfma_f32_32x32x16_bf16(kb3f, qf3, sb, 0, 0, 0);
  };
  auto sm_pv = [&](const f32x16& sa, const f32x16& sb, const char* vread) {
    uint4v u0 = {pk2t(exp2f(sa[0]),  exp2f(sa[1])),  pk2t(exp2f(sa[2]),  exp2f(sa[3])),
                 pk2t(exp2f(sa[4]),  exp2f(sa[5])),  pk2t(exp2f(sa[6]),  exp2f(sa[7]))};
    uint4v u1 = {pk2t(exp2f(sa[8]),  exp2f(sa[9])),  pk2t(exp2f(sa[10]), exp2f(sa[11])),
                 pk2t(exp2f(sa[12]), exp2f(sa[13])), pk2t(exp2f(sa[14]), exp2f(sa[15]))};
    uint4v u2 = {pk2t(exp2f(sb[0]),  exp2f(sb[1])),  pk2t(exp2f(sb[2]),  exp2f(sb[3])),
                 pk2t(exp2f(sb[4]),  exp2f(sb[5])),  pk2t(exp2f(sb[6]),  exp2f(sb[7]))};
    uint4v u3 = {pk2t(exp2f(sb[8]),  exp2f(sb[9])),  pk2t(exp2f(sb[10]), exp2f(sb[11])),
                 pk2t(exp2f(sb[12]), exp2f(sb[13])), pk2t(exp2f(sb[14]), exp2f(sb[15]))};
    const bf16x8 pf0 = __builtin_bit_cast(bf16x8, u0);
    const bf16x8 pf1 = __builtin_bit_cast(bf16x8, u1);
    const bf16x8 pf2 = __builtin_bit_cast(bf16x8, u2);
    const bf16x8 pf3 = __builtin_bit_cast(bf16x8, u3);
    const bf16x8 v00 = *(const bf16x8*)(vread + (0 + hi) * 1024 + ql * 16);
    const bf16x8 v01 = *(const bf16x8*)(vread + (2 + hi) * 1024 + ql * 16);
    const bf16x8 v02 = *(const bf16x8*)(vread + (4 + hi) * 1024 + ql * 16);
    const bf16x8 v03 = *(const bf16x8*)(vread + (6 + hi) * 1024 + ql * 16);
    const bf16x8 v10 = *(const bf16x8*)(vread + (0 + hi) * 1024 + 512 + ql * 16);
    const bf16x8 v11 = *(const bf16x8*)(vread + (2 + hi) * 1024 + 512 + ql * 16);
    const bf16x8 v12 = *(const bf16x8*)(vread + (4 + hi) * 1024 + 512 + ql * 16);
    const bf16x8 v13 = *(const bf16x8*)(vread + (6 + hi) * 1024 + 512 + ql * 16);
    ot0  = __builtin_amdgcn_mfma_f32_32x32x16_bf16(v00,  pf0, ot0, 0, 0, 0);
    ot1  = __builtin_amdgcn_mfma_f32_32x32x16_bf16(v10,  pf0, ot1, 0, 0, 0);
    otls = __builtin_amdgcn_mfma_f32_32x32x16_bf16(ones, pf0, otls, 0, 0, 0);
    ot0  = __builtin_amdgcn_mfma_f32_32x32x16_bf16(v01,  pf1, ot0, 0, 0, 0);
    ot1  = __builtin_amdgcn_mfma_f32_32x32x16_bf16(v11,  pf1, ot1, 0, 0, 0);
    otls = __builtin_amdgcn_mfma_f32_32x32x16_bf16(ones, pf1, otls, 0, 0, 0);
    ot0  = __builtin_amdgcn_mfma_f32_32x32x16_bf16(v02,  pf2, ot0, 0, 0, 0);
    ot1  = __builtin_amdgcn_mfma_f32_32x32x16_bf16(v12,  pf2, ot1, 0, 0, 0);
    otls = __builtin_amdgcn_mfma_f32_32x32x16_bf16(ones, pf2, otls, 0, 0, 0);
    ot0  = __builtin_amdgcn_mfma_f32_32x32x16_bf16(v03,  pf3, ot0, 0, 0, 0);
    ot1  = __builtin_amdgcn_mfma_f32_32x32x16_bf16(v13,  pf3, ot1, 0, 0, 0);
    otls = __builtin_amdgcn_mfma_f32_32x32x16_bf16(ones, pf3, otls, 0, 0, 0);
  };

  // rotating buffer pointers: k0=kb[j%3], k1=kb[(j+1)%3], k2=kb[(j+2)%3]; same v.
  char *k0 = smem,          *k1 = smem + 8192,          *k2 = smem + 16384;
  char *v0 = smem + 24576,  *v1 = smem + 32768,         *v2 = smem + 40960;

  // prologue: K(0),V(0),K(1),V(1),K(2) issued (10 loads); vmcnt(8) -> K(0) done
  stageK(0, k0);
  stageV(0, v0);
  stageK(1, k1);
  stageV(1, v1);
  stageK(2, k2);
  asm volatile("s_waitcnt vmcnt(8)" ::: "memory");
  __builtin_amdgcn_sched_barrier(0);
  __builtin_amdgcn_s_barrier();
  f32x16 sca = {}, scb = {};
  qk(k0, sca, scb);   // s(0)

  for (int j = 0; j < 32; ++j) {
    // forces V(j),K(j+1) done (issued 2 barrier-intervals ago);
    // V(j+1),K(j+2) remain in flight across the barrier.
    if (j <= 29)      asm volatile("s_waitcnt vmcnt(4)" ::: "memory");
    else if (j == 30) asm volatile("s_waitcnt vmcnt(2)" ::: "memory");
    else              asm volatile("s_waitcnt vmcnt(0)" ::: "memory");
    __builtin_amdgcn_sched_barrier(0);
    __builtin_amdgcn_s_barrier();       // all waves: tile j ready, iter j-1 reads done
    if (j + 2 < 32) stageV(j + 2, v2);  // vb[(j+2)%3]: last read at iter j-1 -> safe
    if (j + 3 < 32) stageK(j + 3, k0);  // kb[j%3]: last read at qk(j-1) -> safe
    f32x16 sna = {}, snb = {};
    __builtin_amdgcn_s_setprio(1);
    if (j < 31) qk(k1, sna, snb);       // QK(j+1) on MFMA pipe
    sm_pv(sca, scb, v0);                // exp/pack in QK's shadow, then PV(j)
    __builtin_amdgcn_s_setprio(0);
    sca = sna; scb = snb;
    // rotate
    char* tk = k0; k0 = k1; k1 = k2; k2 = tk;
    char* tv = v0; v0 = v1; v1 = v2; v2 = tv;
  }

  __syncthreads();  // all iters done before epilogue reuses kb region

  // epilogue: normalize, transpose via XOR-swizzled LDS (reuse smem), store
  const float inv = 1.0f / otls[0];
  bf16_t* ob = (bf16_t*)(smem + w * 4096);
#pragma unroll
  for (int rg = 0; rg < 4; ++rg) {
    const int d0 = rg * 8 + hi * 4;
    bf16x4 w0, w1;
#pragma unroll
    for (int j = 0; j < 4; ++j) {
      w0[j] = (bf16_t)(ot0[4 * rg + j] * inv);
      w1[j] = (bf16_t)(ot1[4 * rg + j] * inv);
    }
    *(bf16x4*)((char*)ob + ql * 128 + (((d0)      * 2) ^ ((ql & 7) << 4))) = w0;
    *(bf16x4*)((char*)ob + ql * 128 + (((d0 + 32) * 2) ^ ((ql & 7) << 4))) = w1;
  }
  __syncthreads();
#pragma unroll
  for (int i = 0; i < 4; ++i) {
    const int c = i * 64 + l;
    const int qq = c >> 3, ch = c & 7;
    bf16x8 vv = *(const bf16x8*)((char*)ob + qq * 128 + ((ch * 16) ^ ((qq & 7) << 4)));
    *(bf16x8*)(Ao + (size_t)(b * 2048 + q0 + qq) * 1024 + h * 64 + ch * 8) = vv;
  }
}

// ---------------- launcher ----------------

extern "C" void kernel_launch(void* const* d_in, const int* in_sizes, int n_in,
                              void* d_out, int out_size, void* d_ws, size_t ws_size,
                              hipStream_t stream) {
  const float* x    = (const float*)d_in[0];  // [2,2048,1024]
  const float* wqkv = (const float*)d_in[1];  // [1024,3072]
  const float* wo   = (const float*)d_in[2];  // [1024,1024]
  float* out = (float*)d_out;

  char* ws = (char*)d_ws;
  bf16_t* xb    = (bf16_t*)(ws);                        // 8 MB  [4096][1024]
  bf16_t* wqkvT = (bf16_t*)(ws + (size_t)(8u  << 20));  // 6 MB  [3072][1024]
  bf16_t* woT   = (bf16_t*)(ws + (size_t)(14u << 20));  // 2 MB  [1024][1024]
  bf16_t* Qb    = (bf16_t*)(ws + (size_t)(16u << 20));  // 8 MB  [32][2048][64]
  bf16_t* Kb    = (bf16_t*)(ws + (size_t)(24u << 20));  // 8 MB
  bf16_t* Vtb   = (bf16_t*)(ws + (size_t)(32u << 20));  // 8 MB  [32][64][2048] (kv-permuted)
  bf16_t* attn  = (bf16_t*)(ws + (size_t)(40u << 20));  // 8 MB  [4096][1024]

  prep_k<<<6144, 256, 0, stream>>>(x, xb, wqkv, wqkvT, wo, woT);
  gemm_qkv_k<<<dim3(32, 24), 256, 0, stream>>>(xb, wqkvT, Qb, Kb, Vtb);
  attn_k<<<dim3(16, 32), 256, 0, stream>>>(Qb, Kb, Vtb, attn);
  gemm_o_k<<<dim3(32, 8), 256, 0, stream>>>(attn, woT, out);
}

// Round 16
// 118.072 us; speedup vs baseline: 1.0274x; 1.0274x over previous
//
#include <hip/hip_runtime.h>
#include <hip/hip_bf16.h>
#include <cstdint>

typedef __bf16 bf16_t;
typedef __bf16 bf16x8 __attribute__((ext_vector_type(8)));
typedef __bf16 bf16x4 __attribute__((ext_vector_type(4)));
typedef __bf16 bf16x2 __attribute__((ext_vector_type(2)));
typedef float  f32x4  __attribute__((ext_vector_type(4)));
typedef float  f32x16 __attribute__((ext_vector_type(16)));
typedef unsigned uint4v __attribute__((ext_vector_type(4)));

#define AS1 __attribute__((address_space(1)))
#define AS3 __attribute__((address_space(3)))

static __device__ __forceinline__ void gld_lds16(const void* g, void* l) {
  __builtin_amdgcn_global_load_lds((AS1 void*)g, (AS3 void*)l, 16, 0, 0);
}

// truncation-pack two f32 -> bf16x2 word via one v_perm_b32 (lo=a, hi=b).
static __device__ __forceinline__ unsigned pk2t(float a, float b) {
  return __builtin_amdgcn_perm(__builtin_bit_cast(unsigned, a),
                               __builtin_bit_cast(unsigned, b), 0x03020706u);
}

// ---------------- fused prep: convert x (16B stores) + transpose weights -----
__global__ __launch_bounds__(256) void prep_k(const float* __restrict__ x,
                                              bf16_t* __restrict__ xb,
                                              const float* __restrict__ wqkv,
                                              bf16_t* __restrict__ wqkvT,
                                              const float* __restrict__ wo,
                                              bf16_t* __restrict__ woT) {
  int bid = blockIdx.x;
  if (bid < 2048) {
    const int i = bid * 256 + threadIdx.x;
    float4 v0 = ((const float4*)x)[(size_t)i * 2];
    float4 v1 = ((const float4*)x)[(size_t)i * 2 + 1];
    bf16x8 o;
    o[0] = (bf16_t)v0.x; o[1] = (bf16_t)v0.y; o[2] = (bf16_t)v0.z; o[3] = (bf16_t)v0.w;
    o[4] = (bf16_t)v1.x; o[5] = (bf16_t)v1.y; o[6] = (bf16_t)v1.z; o[7] = (bf16_t)v1.w;
    *(bf16x8*)(xb + (size_t)i * 8) = o;
    return;
  }
  __shared__ float tile[32][33];
  const float* in; bf16_t* out; int N, bx, by;
  if (bid < 5120) { bid -= 2048; in = wqkv; out = wqkvT; N = 3072; bx = bid % 96; by = bid / 96; }
  else            { bid -= 5120; in = wo;   out = woT;   N = 1024; bx = bid & 31; by = bid >> 5; }
  const int t = threadIdx.x, c = t & 31, r0 = t >> 5;
#pragma unroll
  for (int i = 0; i < 4; ++i) {
    int r = r0 + i * 8;
    tile[r][c] = in[(size_t)(by * 32 + r) * N + bx * 32 + c];
  }
  __syncthreads();
#pragma unroll
  for (int i = 0; i < 4; ++i) {
    int r = r0 + i * 8;
    out[(size_t)(bx * 32 + r) * 1024 + by * 32 + c] = (bf16_t)tile[c][r];
  }
}

// ---------------- 128x128 bf16 GEMM core: depth-2 pipeline, swizzled LDS ------
// LDS slot s (16B) of a tile holds row=s>>2, chunk cb=(s&3)^((s>>3)&3):
// source-permuted (T21) so linear gld_lds dest yields a bank-friendly layout.
// 4-lane groups still fetch one 64B row => global coalescing preserved.
// Read addr = row*64 + ((g ^ ((lr>>1)&3))<<4) => 2-way LDS conflict (free).
template <int KDIM>
static __device__ __forceinline__ void gemm128_pipe(const bf16_t* __restrict__ A,
                                                    const bf16_t* __restrict__ Bt,
                                                    char* lds, f32x4 acc[4][4],
                                                    int bm, int bn) {
  constexpr int NK = KDIM / 32;
  const int t = threadIdx.x;
  const int lr = t & 15, g = (t >> 4) & 3;
  const int w = t >> 6, wr = w >> 1, wc = w & 1;
  const int xg = (g ^ ((lr >> 1) & 3)) << 4;

  auto bufA = [&](int i) { return lds + (i % 3) * 8192; };
  auto bufB = [&](int i) { return lds + 24576 + (i % 3) * 8192; };

  auto stage = [&](int i) {
    const int kt = i * 32;
    char* la = bufA(i);
    char* lb = bufB(i);
#pragma unroll
    for (int c = 0; c < 2; ++c) {
      const int idx = c * 256 + t;
      const int row = idx >> 2;
      const int cb = (idx & 3) ^ ((idx >> 3) & 3);   // source-side swizzle
      const int off = ((t & 192) + c * 256) * 16;
      gld_lds16(A  + (size_t)(bm * 128 + row) * KDIM + kt + cb * 8, la + off);
      gld_lds16(Bt + (size_t)(bn * 128 + row) * KDIM + kt + cb * 8, lb + off);
    }
  };

  // prologue: tiles 0 and 1 issued; wait tile 0 (tile 1 stays in flight)
  stage(0);
  stage(1);
  asm volatile("s_waitcnt vmcnt(4)" ::: "memory");
  __builtin_amdgcn_sched_barrier(0);
  __builtin_amdgcn_s_barrier();

  for (int j = 0; j < NK; ++j) {
    if (j + 2 < NK) {
      stage(j + 2);
      asm volatile("s_waitcnt vmcnt(8)" ::: "memory");   // stage(j) done
    } else if (j + 1 < NK) {
      asm volatile("s_waitcnt vmcnt(4)" ::: "memory");
    } else {
      asm volatile("s_waitcnt vmcnt(0)" ::: "memory");
    }
    __builtin_amdgcn_sched_barrier(0);
    __builtin_amdgcn_s_barrier();        // tile j resident for all waves
    const char* laR = bufA(j);
    const char* lbR = bufB(j);
    bf16x8 af[4], bv[4];
#pragma unroll
    for (int mi = 0; mi < 4; ++mi)
      af[mi] = *(const bf16x8*)(laR + (wr * 64 + mi * 16 + lr) * 64 + xg);
#pragma unroll
    for (int ni = 0; ni < 4; ++ni)
      bv[ni] = *(const bf16x8*)(lbR + (wc * 64 + ni * 16 + lr) * 64 + xg);
    __builtin_amdgcn_s_setprio(1);
#pragma unroll
    for (int mi = 0; mi < 4; ++mi)
#pragma unroll
      for (int ni = 0; ni < 4; ++ni)
        acc[mi][ni] = __builtin_amdgcn_mfma_f32_16x16x32_bf16(af[mi], bv[ni], acc[mi][ni], 0, 0, 0);
    __builtin_amdgcn_s_setprio(0);
    __builtin_amdgcn_sched_barrier(0);
    __builtin_amdgcn_s_barrier();        // reads consumed before next restage
  }
}

// GEMM1: qkv = x @ Wqkv ; Q PRE-SCALED by log2(e)/sqrt(64); V stored with
// quad-swapped kv order so attn PV A-fragments are contiguous 16B in LDS.
__global__ __launch_bounds__(256) void gemm_qkv_k(const bf16_t* __restrict__ xb,
                                                  const bf16_t* __restrict__ wt,
                                                  bf16_t* __restrict__ Qo,
                                                  bf16_t* __restrict__ Ko,
                                                  bf16_t* __restrict__ Vto) {
  __shared__ __align__(16) char lds[49152];
  const int bm = blockIdx.x, bn = blockIdx.y;
  f32x4 acc[4][4] = {};
  gemm128_pipe<1024>(xb, wt, lds, acc, bm, bn);
  const float cs = 0.18033688011112042f;
  const int t = threadIdx.x, lr = t & 15, g = (t >> 4) & 3, w = t >> 6, wr = w >> 1, wc = w & 1;
  const int row0 = bm * 128 + wr * 64, col0 = bn * 128 + wc * 64;
#pragma unroll
  for (int mi = 0; mi < 4; ++mi) {
    const int row = row0 + mi * 16 + g * 4;
    const int b = row >> 11, s = row & 2047;
#pragma unroll
    for (int ni = 0; ni < 4; ++ni) {
      const int col = col0 + ni * 16 + lr;
      const int t3 = col >> 10, rem = col & 1023, h = rem >> 6, d = rem & 63;
      const int bh = b * 16 + h;
#pragma unroll
      for (int r = 0; r < 4; ++r) {
        const float av = acc[mi][ni][r];
        if (t3 == 0)      Qo[((size_t)bh * 2048 + s + r) * 64 + d] = (bf16_t)(av * cs);
        else if (t3 == 1) Ko[((size_t)bh * 2048 + s + r) * 64 + d] = (bf16_t)av;
        else {
          const int kv = s + r;
          const int q3 = (kv >> 2) & 7;
          const int dq = (q3 & 4) | ((q3 & 1) << 1) | ((q3 >> 1) & 1);
          const int kvp = (kv & ~31) | (dq << 2) | (kv & 3);
          Vto[((size_t)bh * 64 + d) * 2048 + kvp] = (bf16_t)av;
        }
      }
    }
  }
}

// ---------------- gemm_o: 128x64 tiles (512 blocks => 2 blocks/CU) -----------
// A 128x32 (2 loads/thread), B 64x32 (1 load/thread); same source-swizzle.
static __device__ __forceinline__ void gemm_o_pipe(const bf16_t* __restrict__ A,
                                                   const bf16_t* __restrict__ Bt,
                                                   char* lds, f32x4 acc[4][2],
                                                   int bm, int bn) {
  constexpr int NK = 32;
  const int t = threadIdx.x;
  const int lr = t & 15, g = (t >> 4) & 3;
  const int w = t >> 6, wr = w >> 1, wc = w & 1;
  const int xg = (g ^ ((lr >> 1) & 3)) << 4;

  auto bufA = [&](int i) { return lds + (i % 3) * 8192; };
  auto bufB = [&](int i) { return lds + 24576 + (i % 3) * 4096; };

  auto stage = [&](int i) {
    const int kt = i * 32;
    char* la = bufA(i);
    char* lb = bufB(i);
#pragma unroll
    for (int c = 0; c < 2; ++c) {
      const int idx = c * 256 + t;
      const int row = idx >> 2;
      const int cb = (idx & 3) ^ ((idx >> 3) & 3);
      const int off = ((t & 192) + c * 256) * 16;
      gld_lds16(A + (size_t)(bm * 128 + row) * 1024 + kt + cb * 8, la + off);
    }
    const int rowb = t >> 2;
    const int cbb = (t & 3) ^ ((t >> 3) & 3);
    gld_lds16(Bt + (size_t)(bn * 64 + rowb) * 1024 + kt + cbb * 8, lb + (t & 192) * 16);
  };

  stage(0);
  stage(1);
  asm volatile("s_waitcnt vmcnt(3)" ::: "memory");
  __builtin_amdgcn_sched_barrier(0);
  __builtin_amdgcn_s_barrier();

  for (int j = 0; j < NK; ++j) {
    if (j + 2 < NK) {
      stage(j + 2);
      asm volatile("s_waitcnt vmcnt(6)" ::: "memory");
    } else if (j + 1 < NK) {
      asm volatile("s_waitcnt vmcnt(3)" ::: "memory");
    } else {
      asm volatile("s_waitcnt vmcnt(0)" ::: "memory");
    }
    __builtin_amdgcn_sched_barrier(0);
    __builtin_amdgcn_s_barrier();
    const char* laR = bufA(j);
    const char* lbR = bufB(j);
    bf16x8 af[4], bv[2];
#pragma unroll
    for (int mi = 0; mi < 4; ++mi)
      af[mi] = *(const bf16x8*)(laR + (wr * 64 + mi * 16 + lr) * 64 + xg);
#pragma unroll
    for (int ni = 0; ni < 2; ++ni)
      bv[ni] = *(const bf16x8*)(lbR + (wc * 32 + ni * 16 + lr) * 64 + xg);
    __builtin_amdgcn_s_setprio(1);
#pragma unroll
    for (int mi = 0; mi < 4; ++mi)
#pragma unroll
      for (int ni = 0; ni < 2; ++ni)
        acc[mi][ni] = __builtin_amdgcn_mfma_f32_16x16x32_bf16(af[mi], bv[ni], acc[mi][ni], 0, 0, 0);
    __builtin_amdgcn_s_setprio(0);
    __builtin_amdgcn_sched_barrier(0);
    __builtin_amdgcn_s_barrier();
  }
}

__global__ __launch_bounds__(256) void gemm_o_k(const bf16_t* __restrict__ attn,
                                                const bf16_t* __restrict__ wot,
                                                float* __restrict__ out) {
  __shared__ __align__(16) char lds[36864];
  const int bm = blockIdx.x, bn = blockIdx.y;
  f32x4 acc[4][2] = {};
  gemm_o_pipe(attn, wot, lds, acc, bm, bn);
  const int t = threadIdx.x, lr = t & 15, g = (t >> 4) & 3, w = t >> 6, wr = w >> 1, wc = w & 1;
  const int row0 = bm * 128 + wr * 64, col0 = bn * 64 + wc * 32;
#pragma unroll
  for (int mi = 0; mi < 4; ++mi) {
    const int row = row0 + mi * 16 + g * 4;
#pragma unroll
    for (int ni = 0; ni < 2; ++ni) {
      const int col = col0 + ni * 16 + lr;
#pragma unroll
      for (int r = 0; r < 4; ++r)
        out[(size_t)(row + r) * 1024 + col] = acc[mi][ni][r];
    }
  }
}

// ---------------- flash attention: counted-vmcnt pipeline (r14 exact) ---------
__global__ __launch_bounds__(256, 2) void attn_k(const bf16_t* __restrict__ Q,
                                                 const bf16_t* __restrict__ K,
                                                 const bf16_t* __restrict__ Vt,
                                                 bf16_t* __restrict__ Ao) {
  __shared__ __align__(16) char smem[32768];  // kb0,kb1,vb0,vb1 (8KB each)
  const int t = threadIdx.x, w = t >> 6, l = t & 63;
  const int ql = l & 31, hi = l >> 5;
  const int orig = blockIdx.y * 16 + blockIdx.x;
  const int swz = (orig & 7) * 64 + (orig >> 3);
  const int qblk = swz & 15, bh = swz >> 4;
  const int b = bh >> 4, h = bh & 15;
  const bf16_t* Qb = Q  + (size_t)bh * 2048 * 64;
  const bf16_t* Kb = K  + (size_t)bh * 2048 * 64;
  const bf16_t* Vb = Vt + (size_t)bh * 64 * 2048;
  const int q0 = qblk * 128 + w * 32;

  const bf16_t* ksrc = Kb + (size_t)l * 64 + w * 8;
  const bf16_t* vsrc = Vb + (size_t)l * 2048 + w * 8;

  char* const kb0 = smem;
  char* const kb1 = smem + 8192;
  char* const vb0 = smem + 16384;
  char* const vb1 = smem + 24576;

  const bf16_t* qp = Qb + (size_t)(q0 + ql) * 64 + hi * 8;
  const bf16x8 qf0 = *(const bf16x8*)(qp);
  const bf16x8 qf1 = *(const bf16x8*)(qp + 16);
  const bf16x8 qf2 = *(const bf16x8*)(qp + 32);
  const bf16x8 qf3 = *(const bf16x8*)(qp + 48);

  bf16x8 ones;
#pragma unroll
  for (int i = 0; i < 8; ++i) ones[i] = (bf16_t)1.0f;

  f32x16 ot0 = {}, ot1 = {}, otls = {};

  auto stageK = [&](int tile, char* dst) {
    const bf16_t* ks = ksrc + (size_t)tile * 4096;
    gld_lds16(ks,      dst + w * 1024);
    gld_lds16(ks + 32, dst + (4 + w) * 1024);
  };
  auto stageV = [&](int tile, char* dst) {
    const bf16_t* vs = vsrc + (size_t)tile * 64;
    gld_lds16(vs,      dst + w * 1024);
    gld_lds16(vs + 32, dst + (4 + w) * 1024);
  };
  auto qk = [&](const char* kbuf, f32x16& sa, f32x16& sb) {
    const bf16x8 ka0 = *(const bf16x8*)(kbuf + (0 + hi) * 1024 + ql * 16);
    const bf16x8 ka1 = *(const bf16x8*)(kbuf + (2 + hi) * 1024 + ql * 16);
    const bf16x8 ka2 = *(const bf16x8*)(kbuf + (4 + hi) * 1024 + ql * 16);
    const bf16x8 ka3 = *(const bf16x8*)(kbuf + (6 + hi) * 1024 + ql * 16);
    sa = __builtin_amdgcn_mfma_f32_32x32x16_bf16(ka0, qf0, sa, 0, 0, 0);
    sa = __builtin_amdgcn_mfma_f32_32x32x16_bf16(ka1, qf1, sa, 0, 0, 0);
    sa = __builtin_amdgcn_mfma_f32_32x32x16_bf16(ka2, qf2, sa, 0, 0, 0);
    sa = __builtin_amdgcn_mfma_f32_32x32x16_bf16(ka3, qf3, sa, 0, 0, 0);
    const bf16x8 kb0f = *(const bf16x8*)(kbuf + (0 + hi) * 1024 + 512 + ql * 16);
    const bf16x8 kb1f = *(const bf16x8*)(kbuf + (2 + hi) * 1024 + 512 + ql * 16);
    const bf16x8 kb2f = *(const bf16x8*)(kbuf + (4 + hi) * 1024 + 512 + ql * 16);
    const bf16x8 kb3f = *(const bf16x8*)(kbuf + (6 + hi) * 1024 + 512 + ql * 16);
    sb = __builtin_amdgcn_mfma_f32_32x32x16_bf16(kb0f, qf0, sb, 0, 0, 0);
    sb = __builtin_amdgcn_mfma_f32_32x32x16_bf16(kb1f, qf1, sb, 0, 0, 0);
    sb = __builtin_amdgcn_mfma_f32_32x32x16_bf16(kb2f, qf2, sb, 0, 0, 0);
    sb = __builtin_amdgcn_mfma_f32_32x32x16_bf16(kb3f, qf3, sb, 0, 0, 0);
  };
  auto sm_pv = [&](const f32x16& sa, const f32x16& sb, const char* vread) {
    uint4v u0 = {pk2t(exp2f(sa[0]),  exp2f(sa[1])),  pk2t(exp2f(sa[2]),  exp2f(sa[3])),
                 pk2t(exp2f(sa[4]),  exp2f(sa[5])),  pk2t(exp2f(sa[6]),  exp2f(sa[7]))};
    uint4v u1 = {pk2t(exp2f(sa[8]),  exp2f(sa[9])),  pk2t(exp2f(sa[10]), exp2f(sa[11])),
                 pk2t(exp2f(sa[12]), exp2f(sa[13])), pk2t(exp2f(sa[14]), exp2f(sa[15]))};
    uint4v u2 = {pk2t(exp2f(sb[0]),  exp2f(sb[1])),  pk2t(exp2f(sb[2]),  exp2f(sb[3])),
                 pk2t(exp2f(sb[4]),  exp2f(sb[5])),  pk2t(exp2f(sb[6]),  exp2f(sb[7]))};
    uint4v u3 = {pk2t(exp2f(sb[8]),  exp2f(sb[9])),  pk2t(exp2f(sb[10]), exp2f(sb[11])),
                 pk2t(exp2f(sb[12]), exp2f(sb[13])), pk2t(exp2f(sb[14]), exp2f(sb[15]))};
    const bf16x8 pf0 = __builtin_bit_cast(bf16x8, u0);
    const bf16x8 pf1 = __builtin_bit_cast(bf16x8, u1);
    const bf16x8 pf2 = __builtin_bit_cast(bf16x8, u2);
    const bf16x8 pf3 = __builtin_bit_cast(bf16x8, u3);
    const bf16x8 v00 = *(const bf16x8*)(vread + (0 + hi) * 1024 + ql * 16);
    const bf16x8 v01 = *(const bf16x8*)(vread + (2 + hi) * 1024 + ql * 16);
    const bf16x8 v02 = *(const bf16x8*)(vread + (4 + hi) * 1024 + ql * 16);
    const bf16x8 v03 = *(const bf16x8*)(vread + (6 + hi) * 1024 + ql * 16);
    const bf16x8 v10 = *(const bf16x8*)(vread + (0 + hi) * 1024 + 512 + ql * 16);
    const bf16x8 v11 = *(const bf16x8*)(vread + (2 + hi) * 1024 + 512 + ql * 16);
    const bf16x8 v12 = *(const bf16x8*)(vread + (4 + hi) * 1024 + 512 + ql * 16);
    const bf16x8 v13 = *(const bf16x8*)(vread + (6 + hi) * 1024 + 512 + ql * 16);
    ot0  = __builtin_amdgcn_mfma_f32_32x32x16_bf16(v00,  pf0, ot0, 0, 0, 0);
    ot1  = __builtin_amdgcn_mfma_f32_32x32x16_bf16(v10,  pf0, ot1, 0, 0, 0);
    otls = __builtin_amdgcn_mfma_f32_32x32x16_bf16(ones, pf0, otls, 0, 0, 0);
    ot0  = __builtin_amdgcn_mfma_f32_32x32x16_bf16(v01,  pf1, ot0, 0, 0, 0);
    ot1  = __builtin_amdgcn_mfma_f32_32x32x16_bf16(v11,  pf1, ot1, 0, 0, 0);
    otls = __builtin_amdgcn_mfma_f32_32x32x16_bf16(ones, pf1, otls, 0, 0, 0);
    ot0  = __builtin_amdgcn_mfma_f32_32x32x16_bf16(v02,  pf2, ot0, 0, 0, 0);
    ot1  = __builtin_amdgcn_mfma_f32_32x32x16_bf16(v12,  pf2, ot1, 0, 0, 0);
    otls = __builtin_amdgcn_mfma_f32_32x32x16_bf16(ones, pf2, otls, 0, 0, 0);
    ot0  = __builtin_amdgcn_mfma_f32_32x32x16_bf16(v03,  pf3, ot0, 0, 0, 0);
    ot1  = __builtin_amdgcn_mfma_f32_32x32x16_bf16(v13,  pf3, ot1, 0, 0, 0);
    otls = __builtin_amdgcn_mfma_f32_32x32x16_bf16(ones, pf3, otls, 0, 0, 0);
  };

  stageK(0, kb0);
  stageV(0, vb0);
  stageK(1, kb1);
  asm volatile("s_waitcnt vmcnt(4)" ::: "memory");
  __builtin_amdgcn_sched_barrier(0);
  __builtin_amdgcn_s_barrier();
  f32x16 sca = {}, scb = {};
  qk(kb0, sca, scb);
  __builtin_amdgcn_s_barrier();

  auto body = [&](int j, char* kstage, const char* kread, const char* vread, char* vstage) {
    if (j < 31) stageV(j + 1, vstage);
    if (j < 30) stageK(j + 2, kstage);
    if (j < 30)      asm volatile("s_waitcnt vmcnt(4)" ::: "memory");
    else if (j == 30) asm volatile("s_waitcnt vmcnt(2)" ::: "memory");
    else             asm volatile("s_waitcnt vmcnt(0)" ::: "memory");
    __builtin_amdgcn_sched_barrier(0);
    __builtin_amdgcn_s_barrier();
    f32x16 sna = {}, snb = {};
    __builtin_amdgcn_s_setprio(1);
    if (j < 31) qk(kread, sna, snb);
    sm_pv(sca, scb, vread);
    __builtin_amdgcn_s_setprio(0);
    __builtin_amdgcn_sched_barrier(0);
    __builtin_amdgcn_s_barrier();
    sca = sna; scb = snb;
  };

#pragma unroll 2
  for (int j = 0; j < 32; ++j) {
    if ((j & 1) == 0) body(j, kb0, kb1, vb0, vb1);
    else              body(j, kb1, kb0, vb1, vb0);
  }

  const float inv = 1.0f / otls[0];
  bf16_t* ob = (bf16_t*)(smem + w * 4096);
#pragma unroll
  for (int rg = 0; rg < 4; ++rg) {
    const int d0 = rg * 8 + hi * 4;
    bf16x4 v0, v1;
#pragma unroll
    for (int j = 0; j < 4; ++j) {
      v0[j] = (bf16_t)(ot0[4 * rg + j] * inv);
      v1[j] = (bf16_t)(ot1[4 * rg + j] * inv);
    }
    *(bf16x4*)((char*)ob + ql * 128 + (((d0)      * 2) ^ ((ql & 7) << 4))) = v0;
    *(bf16x4*)((char*)ob + ql * 128 + (((d0 + 32) * 2) ^ ((ql & 7) << 4))) = v1;
  }
  __syncthreads();
#pragma unroll
  for (int i = 0; i < 4; ++i) {
    const int c = i * 64 + l;
    const int qq = c >> 3, ch = c & 7;
    bf16x8 vv = *(const bf16x8*)((char*)ob + qq * 128 + ((ch * 16) ^ ((qq & 7) << 4)));
    *(bf16x8*)(Ao + (size_t)(b * 2048 + q0 + qq) * 1024 + h * 64 + ch * 8) = vv;
  }
}

// ---------------- launcher ----------------

extern "C" void kernel_launch(void* const* d_in, const int* in_sizes, int n_in,
                              void* d_out, int out_size, void* d_ws, size_t ws_size,
                              hipStream_t stream) {
  const float* x    = (const float*)d_in[0];  // [2,2048,1024]
  const float* wqkv = (const float*)d_in[1];  // [1024,3072]
  const float* wo   = (const float*)d_in[2];  // [1024,1024]
  float* out = (float*)d_out;

  char* ws = (char*)d_ws;
  bf16_t* xb    = (bf16_t*)(ws);                        // 8 MB  [4096][1024]
  bf16_t* wqkvT = (bf16_t*)(ws + (size_t)(8u  << 20));  // 6 MB  [3072][1024]
  bf16_t* woT   = (bf16_t*)(ws + (size_t)(14u << 20));  // 2 MB  [1024][1024]
  bf16_t* Qb    = (bf16_t*)(ws + (size_t)(16u << 20));  // 8 MB  [32][2048][64]
  bf16_t* Kb    = (bf16_t*)(ws + (size_t)(24u << 20));  // 8 MB
  bf16_t* Vtb   = (bf16_t*)(ws + (size_t)(32u << 20));  // 8 MB  [32][64][2048] (kv-permuted)
  bf16_t* attn  = (bf16_t*)(ws + (size_t)(40u << 20));  // 8 MB  [4096][1024]

  prep_k<<<6144, 256, 0, stream>>>(x, xb, wqkv, wqkvT, wo, woT);
  gemm_qkv_k<<<dim3(32, 24), 256, 0, stream>>>(xb, wqkvT, Qb, Kb, Vtb);
  attn_k<<<dim3(16, 32), 256, 0, stream>>>(Qb, Kb, Vtb, attn);
  gemm_o_k<<<dim3(32, 16), 256, 0, stream>>>(attn, woT, out);
}